// Round 1
// baseline (820.013 us; speedup 1.0000x reference)
//
#include <hip/hip_runtime.h>
#include <math.h>

#define B_ 32
#define C_ 40000
#define D_ 2048
#define T_SCALE 10.0f
#define P_MARG 0.2f
#define N_MARG 0.3f
#define KSPLIT 8
#define KCH (D_ / KSPLIT) // 256

// ---- workspace layout (in floats) ----
#define AT_OFF 0
#define AT_FLOATS (D_ * 64) // 131072 : A^T [2048][64]
#define NS_OFF AT_FLOATS    // nsims [32][C]
#define NS_FLOATS (B_ * C_)
#define VR_OFF (NS_OFF + NS_FLOATS) // vrow [C]
#define VR_FLOATS C_
#define SC_OFF (VR_OFF + VR_FLOATS) // scalars
#define S_HLOSS 0
#define S_THSUM 1
#define S_THCNT 2
#define S_BAD 3
#define S_NTH 4  // 32 floats
#define S_BU 36  // 32 floats
#define SC_FLOATS 128
#define WS_FLOATS_TOTAL (SC_OFF + SC_FLOATS)

__device__ __forceinline__ float softplus_f(float x) {
    // stable log(1+exp(x))
    return (x > 0.f) ? (x + log1pf(expf(-x))) : log1pf(expf(x));
}

// ---- K1a: build At[k][a] = a<32 ? inputs[a][k] : V[targets[a-32]][k] ----
__global__ __launch_bounds__(256) void build_At(const float* __restrict__ in,
                                                const float* __restrict__ V,
                                                const int* __restrict__ tgt,
                                                float* __restrict__ At) {
    int k = blockIdx.x * 256 + threadIdx.x;
    if (k >= D_) return;
#pragma unroll
    for (int a = 0; a < 32; ++a) At[(size_t)k * 64 + a] = in[(size_t)a * D_ + k];
    for (int a = 0; a < 32; ++a) {
        int t = tgt[a];
        At[(size_t)k * 64 + 32 + a] = V[(size_t)t * D_ + k];
    }
}

// ---- K1b: sims (32x32), h_loss, n_th_t[b] ----
__global__ __launch_bounds__(1024) void small_losses(const float* __restrict__ in,
                                                     const float* __restrict__ V,
                                                     const int* __restrict__ tgt,
                                                     float* __restrict__ ws) {
    __shared__ float dots[32][33];
    __shared__ float sims[32][33];
    __shared__ float nthr[32], pthr[32];
    __shared__ int ts[32];
    __shared__ float red[4];
    int tid = threadIdx.x;
    int i = tid >> 5, j = tid & 31;
    if (tid < 32) ts[tid] = tgt[tid];
    if (tid < 4) red[tid] = 0.f;

    const float4* a4 = (const float4*)(in + (size_t)i * D_);
    const float4* b4 = (const float4*)(in + (size_t)j * D_);
    float s = 0.f;
    for (int k = 0; k < D_ / 4; ++k) {
        float4 x = a4[k], y = b4[k];
        s += x.x * y.x + x.y * y.y + x.z * y.z + x.w * y.w;
    }
    dots[i][j] = s;
    __syncthreads();
    float sim = dots[i][j] * rsqrtf(dots[i][i] * dots[j][j]);
    sims[i][j] = sim;
    __syncthreads();
    if (tid < 32) {
        float nmin = 2.f, pmax = -2.f;
        int ti = ts[tid];
        for (int jj = 0; jj < 32; ++jj) {
            bool pos = (ts[jj] == ti) && (jj != tid);
            float v = sims[tid][jj];
            if (pos) {
                nmin = fminf(nmin, v);
                pmax = fmaxf(pmax, v);
            }
        }
        nthr[tid] = nmin - N_MARG;
        pthr[tid] = pmax - P_MARG;
    }
    __syncthreads();
    bool pos = (ts[i] == ts[j]) && (i != j);
    bool neg = (ts[i] != ts[j]);
    float hp = 0.f, hpc = 0.f, hn = 0.f, hnc = 0.f;
    if (pos && sim < pthr[i]) { hp = softplus_f(-sim); hpc = 1.f; }
    if (neg && sim > nthr[i]) { hn = softplus_f(sim); hnc = 1.f; }
    if (hpc != 0.f) { atomicAdd(&red[0], hp); atomicAdd(&red[1], hpc); }
    if (hnc != 0.f) { atomicAdd(&red[2], hn); atomicAdd(&red[3], hnc); }

    // n_th_t: group i (32 lanes j) computes dot(in[i], V[ts[i]])
    const float4* v4 = (const float4*)(V + (size_t)ts[i] * D_);
    float sn = 0.f;
    for (int k = j; k < D_ / 4; k += 32) {
        float4 x = a4[k], y = v4[k];
        sn += x.x * y.x + x.y * y.y + x.z * y.z + x.w * y.w;
    }
    for (int off = 16; off > 0; off >>= 1) sn += __shfl_down(sn, off, 32);
    if (j == 0) ws[SC_OFF + S_NTH + i] = sn * rsqrtf(dots[i][i]) - N_MARG;
    __syncthreads();
    if (tid == 0) {
        float h = 0.f;
        if (red[1] > 0.f) h += red[0] / red[1];
        if (red[3] > 0.f) h += red[2] / red[3];
        ws[SC_OFF + S_HLOSS] = h;
    }
}

// ---- K2: fused 64-row GEMM over V, K-split with atomic partials ----
__global__ __launch_bounds__(256) void big_gemm(const float* __restrict__ At,
                                                const float* __restrict__ V,
                                                float* __restrict__ out,   // [32][C], pre-zeroed
                                                float* __restrict__ nsims, // [32][C], pre-zeroed
                                                float* __restrict__ vrow)  // [C], pre-zeroed
{
    int c = blockIdx.x * 256 + threadIdx.x;
    if (c >= C_) return;
    int k0 = blockIdx.y * KCH;
    const float* vp = V + (size_t)c * D_ + k0;
    const float* ap = At + (size_t)k0 * 64;
    float acc[64];
#pragma unroll
    for (int a = 0; a < 64; ++a) acc[a] = 0.f;
    float vsum = 0.f;
    for (int kk = 0; kk < KCH; kk += 4) {
        float4 v = *(const float4*)(vp + kk);
        vsum += v.x + v.y + v.z + v.w;
        const float* a0 = ap + (size_t)kk * 64;
#pragma unroll
        for (int a = 0; a < 64; ++a) acc[a] = fmaf(a0[a], v.x, acc[a]);
#pragma unroll
        for (int a = 0; a < 64; ++a) acc[a] = fmaf(a0[64 + a], v.y, acc[a]);
#pragma unroll
        for (int a = 0; a < 64; ++a) acc[a] = fmaf(a0[128 + a], v.z, acc[a]);
#pragma unroll
        for (int a = 0; a < 64; ++a) acc[a] = fmaf(a0[192 + a], v.w, acc[a]);
    }
#pragma unroll
    for (int a = 0; a < 32; ++a) atomicAdd(&out[(size_t)a * C_ + c], acc[a] * T_SCALE);
#pragma unroll
    for (int a = 0; a < 32; ++a) atomicAdd(&nsims[(size_t)a * C_ + c], acc[32 + a]);
    atomicAdd(&vrow[c], vsum);
}

// ---- K3: per-row logsumexp of outputs, bu term ----
__global__ __launch_bounds__(256) void row_lse(const float* __restrict__ out,
                                               const int* __restrict__ tgt,
                                               float* __restrict__ ws) {
    int b = blockIdx.x;
    const float* row = out + (size_t)b * C_;
    __shared__ float sm[256];
    int tid = threadIdx.x;
    float m = -INFINITY;
    for (int c = tid; c < C_; c += 256) m = fmaxf(m, row[c]);
    sm[tid] = m;
    __syncthreads();
    for (int s2 = 128; s2 > 0; s2 >>= 1) {
        if (tid < s2) sm[tid] = fmaxf(sm[tid], sm[tid + s2]);
        __syncthreads();
    }
    float rmax = sm[0];
    __syncthreads();
    float s = 0.f;
    for (int c = tid; c < C_; c += 256) s += expf(row[c] - rmax);
    sm[tid] = s;
    __syncthreads();
    for (int s2 = 128; s2 > 0; s2 >>= 1) {
        if (tid < s2) sm[tid] += sm[tid + s2];
        __syncthreads();
    }
    if (tid == 0) {
        float lse = rmax + logf(sm[0]);
        ws[SC_OFF + S_BU + b] = lse - row[tgt[b]];
    }
}

// ---- K4: th_loss masked sum over nsims ----
__global__ __launch_bounds__(256) void th_reduce(const float* __restrict__ nsims,
                                                 float* __restrict__ ws) {
    int b = blockIdx.y;
    int c = blockIdx.x * 256 + threadIdx.x;
    int tid = threadIdx.x;
    float nth = ws[SC_OFF + S_NTH + b];
    float sum = 0.f, cnt = 0.f;
    if (c < C_) {
        float x = nsims[(size_t)b * C_ + c];
        if (x > nth && x < 0.9999f) { sum = softplus_f(x); cnt = 1.f; }
    }
    __shared__ float ssum[256];
    __shared__ float scnt[256];
    ssum[tid] = sum;
    scnt[tid] = cnt;
    __syncthreads();
    for (int s2 = 128; s2 > 0; s2 >>= 1) {
        if (tid < s2) { ssum[tid] += ssum[tid + s2]; scnt[tid] += scnt[tid + s2]; }
        __syncthreads();
    }
    if (tid == 0 && scnt[0] != 0.f) {
        atomicAdd(&ws[SC_OFF + S_THSUM], ssum[0]);
        atomicAdd(&ws[SC_OFF + S_THCNT], scnt[0]);
    }
}

// ---- K4b: active-flag check (any zero row-sum of V) ----
__global__ __launch_bounds__(256) void vrow_check(const float* __restrict__ vrow,
                                                  float* __restrict__ ws) {
    int c = blockIdx.x * 256 + threadIdx.x;
    if (c < C_ && vrow[c] == 0.0f) ws[SC_OFF + S_BAD] = 1.0f; // idempotent racy write
}

// ---- K5: combine ----
__global__ void finalize(const float* __restrict__ ws, float* __restrict__ out0) {
    if (threadIdx.x == 0 && blockIdx.x == 0) {
        float bu = 0.f;
        for (int b = 0; b < 32; ++b) bu += ws[SC_OFF + S_BU + b];
        bu /= 32.f;
        float h = ws[SC_OFF + S_HLOSS];
        float th = 0.f;
        float cnt = ws[SC_OFF + S_THCNT];
        if (ws[SC_OFF + S_BAD] == 0.f && cnt > 0.f) th = ws[SC_OFF + S_THSUM] / cnt;
        out0[0] = 1.0f * bu + 1.0f * h + 3.0f * th;
    }
}

extern "C" void kernel_launch(void* const* d_in, const int* in_sizes, int n_in,
                              void* d_out, int out_size, void* d_ws, size_t ws_size,
                              hipStream_t stream) {
    const float* in = (const float*)d_in[0];
    const float* V = (const float*)d_in[1];
    const int* tgt = (const int*)d_in[2];
    float* outp = (float*)d_out;
    float* ws = (float*)d_ws;
    float* At = ws + AT_OFF;
    float* nsims = ws + NS_OFF;
    float* vrow = ws + VR_OFF;

    // zero atomic-accumulated regions every call (deterministic across replays)
    hipMemsetAsync(d_out, 0, (size_t)(1 + B_ * C_) * sizeof(float), stream);
    hipMemsetAsync((void*)(ws + NS_OFF), 0,
                   (size_t)(WS_FLOATS_TOTAL - NS_OFF) * sizeof(float), stream);

    build_At<<<(D_ + 255) / 256, 256, 0, stream>>>(in, V, tgt, At);
    small_losses<<<1, 1024, 0, stream>>>(in, V, tgt, ws);

    dim3 g2((C_ + 255) / 256, KSPLIT);
    big_gemm<<<g2, 256, 0, stream>>>(At, V, outp + 1, nsims, vrow);

    row_lse<<<B_, 256, 0, stream>>>(outp + 1, tgt, ws);

    dim3 g4((C_ + 255) / 256, B_);
    th_reduce<<<g4, 256, 0, stream>>>(nsims, ws);
    vrow_check<<<(C_ + 255) / 256, 256, 0, stream>>>(vrow, ws);
    finalize<<<1, 64, 0, stream>>>(ws, outp);
}

// Round 2
// 617.904 us; speedup vs baseline: 1.3271x; 1.3271x over previous
//
#include <hip/hip_runtime.h>
#include <math.h>

#define B_ 32
#define C_ 40000
#define D_ 2048
#define T_SCALE 10.0f
#define P_MARG 0.2f
#define N_MARG 0.3f
#define KSPLIT 8
#define KCH (D_ / KSPLIT) // 256
#define SUB 32            // k-subchunk staged in LDS

// ---- workspace layout (in floats) ----
#define AT_OFF 0
#define AT_FLOATS (D_ * 64) // A^T [2048][64]
#define NS_OFF AT_FLOATS    // nsims [32][C]
#define NS_FLOATS (B_ * C_)
#define VR_OFF (NS_OFF + NS_FLOATS) // vrow [C]
#define VR_FLOATS C_
#define SC_OFF (VR_OFF + VR_FLOATS) // scalars
#define S_HLOSS 0
#define S_THSUM 1
#define S_THCNT 2
#define S_BAD 3
#define S_NTH 4  // 32 floats
#define S_BU 36  // 32 floats
#define SC_FLOATS 128
#define DT_OFF (SC_OFF + SC_FLOATS) // raw batch dots [32][32]
#define DT_FLOATS (32 * 32)
#define WS_FLOATS_TOTAL (DT_OFF + DT_FLOATS)

__device__ __forceinline__ float softplus_f(float x) {
    return (x > 0.f) ? (x + log1pf(expf(-x))) : log1pf(expf(x));
}

// ---- K1a: At[k][a] = a<32 ? inputs[a][k] : V[targets[a-32]][k] ----
__global__ __launch_bounds__(256) void build_At(const float* __restrict__ in,
                                                const float* __restrict__ V,
                                                const int* __restrict__ tgt,
                                                float* __restrict__ At) {
    int k = blockIdx.x * 256 + threadIdx.x;
    if (k >= D_) return;
#pragma unroll
    for (int a = 0; a < 32; ++a) At[(size_t)k * 64 + a] = in[(size_t)a * D_ + k];
    for (int a = 0; a < 32; ++a) {
        int t = tgt[a];
        At[(size_t)k * 64 + 32 + a] = V[(size_t)t * D_ + k];
    }
}

// ---- K1b: raw 32x32 batch dots, spread over 4 blocks ----
__global__ __launch_bounds__(256) void sims_dots(const float* __restrict__ in,
                                                 float* __restrict__ dt) {
    int i = blockIdx.x * 8 + (threadIdx.x >> 5);
    int j = threadIdx.x & 31;
    const float4* a4 = (const float4*)(in + (size_t)i * D_);
    const float4* b4 = (const float4*)(in + (size_t)j * D_);
    float s = 0.f;
    for (int k = 0; k < D_ / 4; ++k) {
        float4 x = a4[k], y = b4[k];
        s += x.x * y.x + x.y * y.y + x.z * y.z + x.w * y.w;
    }
    dt[i * 32 + j] = s;
}

// ---- K1c: sims, thresholds, h_loss, n_th_t ----
__global__ __launch_bounds__(1024) void small_finish(const float* __restrict__ in,
                                                     const float* __restrict__ V,
                                                     const int* __restrict__ tgt,
                                                     float* __restrict__ ws) {
    __shared__ float sims[32][33];
    __shared__ float nthr[32], pthr[32];
    __shared__ int ts[32];
    __shared__ float diag[32];
    __shared__ float red[4];
    int tid = threadIdx.x;
    int i = tid >> 5, j = tid & 31;
    const float* dt = ws + DT_OFF;
    if (tid < 32) { ts[tid] = tgt[tid]; diag[tid] = dt[tid * 32 + tid]; }
    if (tid < 4) red[tid] = 0.f;
    __syncthreads();
    float sim = dt[i * 32 + j] * rsqrtf(diag[i] * diag[j]);
    sims[i][j] = sim;
    __syncthreads();
    if (tid < 32) {
        float nmin = 2.f, pmax = -2.f;
        int ti = ts[tid];
        for (int jj = 0; jj < 32; ++jj) {
            bool pos = (ts[jj] == ti) && (jj != tid);
            float v = sims[tid][jj];
            if (pos) { nmin = fminf(nmin, v); pmax = fmaxf(pmax, v); }
        }
        nthr[tid] = nmin - N_MARG;
        pthr[tid] = pmax - P_MARG;
    }
    __syncthreads();
    bool pos = (ts[i] == ts[j]) && (i != j);
    bool neg = (ts[i] != ts[j]);
    if (pos && sim < pthr[i]) { atomicAdd(&red[0], softplus_f(-sim)); atomicAdd(&red[1], 1.f); }
    if (neg && sim > nthr[i]) { atomicAdd(&red[2], softplus_f(sim)); atomicAdd(&red[3], 1.f); }

    // n_th_t: group i (32 lanes) computes dot(in[i], V[ts[i]])
    const float4* a4 = (const float4*)(in + (size_t)i * D_);
    const float4* v4 = (const float4*)(V + (size_t)ts[i] * D_);
    float sn = 0.f;
    for (int k = j; k < D_ / 4; k += 32) {
        float4 x = a4[k], y = v4[k];
        sn += x.x * y.x + x.y * y.y + x.z * y.z + x.w * y.w;
    }
    for (int off = 16; off > 0; off >>= 1) sn += __shfl_down(sn, off, 32);
    if (j == 0) ws[SC_OFF + S_NTH + i] = sn * rsqrtf(diag[i]) - N_MARG;
    __syncthreads();
    if (tid == 0) {
        float h = 0.f;
        if (red[1] > 0.f) h += red[0] / red[1];
        if (red[3] > 0.f) h += red[2] / red[3];
        ws[SC_OFF + S_HLOSS] = h;
    }
}

// ---- K2: LDS-staged fused 64-row GEMM over V, K-split w/ atomic partials ----
__global__ __launch_bounds__(256) void gemm_lds(const float* __restrict__ At,
                                                const float* __restrict__ V,
                                                float* __restrict__ out,   // [32][C] zeroed
                                                float* __restrict__ nsims, // [32][C] zeroed
                                                float* __restrict__ vrow)  // [C] zeroed
{
    __shared__ float lds[256][SUB + 1];
    const int tid = threadIdx.x;
    const int c0 = blockIdx.x * 256;
    const int c = c0 + tid;
    const int k0 = blockIdx.y * KCH;

    float acc[64];
#pragma unroll
    for (int a = 0; a < 64; ++a) acc[a] = 0.f;
    float vsum = 0.f;

    // staging index: idx = p*256+tid -> row = idx/8, col4 = idx%8 (128B segments)
    const int srow = tid >> 3;
    const int scol = (tid & 7) * 4;

    for (int s = 0; s < KCH / SUB; ++s) {
        const int ks = k0 + s * SUB;
#pragma unroll
        for (int p = 0; p < 8; ++p) {
            int row = p * 32 + srow;
            int gr = c0 + row;
            if (gr < C_) {
                float4 v = *(const float4*)(V + (size_t)gr * D_ + ks + scol);
                lds[row][scol + 0] = v.x;
                lds[row][scol + 1] = v.y;
                lds[row][scol + 2] = v.z;
                lds[row][scol + 3] = v.w;
            }
        }
        __syncthreads();
        const float* a0 = At + (size_t)ks * 64;
#pragma unroll
        for (int kk = 0; kk < SUB; ++kk) {
            float v = lds[tid][kk];
            vsum += v;
            const float* ap = a0 + (size_t)kk * 64;
#pragma unroll
            for (int a = 0; a < 64; ++a) acc[a] = fmaf(ap[a], v, acc[a]);
        }
        __syncthreads();
    }
    if (c < C_) {
#pragma unroll
        for (int a = 0; a < 32; ++a) atomicAdd(&out[(size_t)a * C_ + c], acc[a] * T_SCALE);
#pragma unroll
        for (int a = 0; a < 32; ++a) atomicAdd(&nsims[(size_t)a * C_ + c], acc[32 + a]);
        atomicAdd(&vrow[c], vsum);
    }
}

// ---- K3: per-row logsumexp of outputs ----
__global__ __launch_bounds__(1024) void row_lse(const float* __restrict__ out,
                                                const int* __restrict__ tgt,
                                                float* __restrict__ ws) {
    int b = blockIdx.x;
    const float* row = out + (size_t)b * C_;
    __shared__ float sm[1024];
    int tid = threadIdx.x;
    float m = -INFINITY;
    for (int cc = tid; cc < C_; cc += 1024) m = fmaxf(m, row[cc]);
    sm[tid] = m;
    __syncthreads();
    for (int s2 = 512; s2 > 0; s2 >>= 1) {
        if (tid < s2) sm[tid] = fmaxf(sm[tid], sm[tid + s2]);
        __syncthreads();
    }
    float rmax = sm[0];
    __syncthreads();
    float s = 0.f;
    for (int cc = tid; cc < C_; cc += 1024) s += expf(row[cc] - rmax);
    sm[tid] = s;
    __syncthreads();
    for (int s2 = 512; s2 > 0; s2 >>= 1) {
        if (tid < s2) sm[tid] += sm[tid + s2];
        __syncthreads();
    }
    if (tid == 0) {
        float lse = rmax + logf(sm[0]);
        ws[SC_OFF + S_BU + b] = lse - row[tgt[b]];
    }
}

// ---- K4: th_loss masked sum over nsims ----
__global__ __launch_bounds__(256) void th_reduce(const float* __restrict__ nsims,
                                                 float* __restrict__ ws) {
    int b = blockIdx.y;
    int c = blockIdx.x * 256 + threadIdx.x;
    int tid = threadIdx.x;
    float nth = ws[SC_OFF + S_NTH + b];
    float sum = 0.f, cnt = 0.f;
    if (c < C_) {
        float x = nsims[(size_t)b * C_ + c];
        if (x > nth && x < 0.9999f) { sum = softplus_f(x); cnt = 1.f; }
    }
    __shared__ float ssum[256];
    __shared__ float scnt[256];
    ssum[tid] = sum;
    scnt[tid] = cnt;
    __syncthreads();
    for (int s2 = 128; s2 > 0; s2 >>= 1) {
        if (tid < s2) { ssum[tid] += ssum[tid + s2]; scnt[tid] += scnt[tid + s2]; }
        __syncthreads();
    }
    if (tid == 0 && scnt[0] != 0.f) {
        atomicAdd(&ws[SC_OFF + S_THSUM], ssum[0]);
        atomicAdd(&ws[SC_OFF + S_THCNT], scnt[0]);
    }
}

// ---- K4b: active-flag (any zero V row-sum) ----
__global__ __launch_bounds__(256) void vrow_check(const float* __restrict__ vrow,
                                                  float* __restrict__ ws) {
    int c = blockIdx.x * 256 + threadIdx.x;
    if (c < C_ && vrow[c] == 0.0f) ws[SC_OFF + S_BAD] = 1.0f;
}

// ---- K5: combine ----
__global__ void finalize(const float* __restrict__ ws, float* __restrict__ out0) {
    if (threadIdx.x == 0 && blockIdx.x == 0) {
        float bu = 0.f;
        for (int b = 0; b < 32; ++b) bu += ws[SC_OFF + S_BU + b];
        bu /= 32.f;
        float h = ws[SC_OFF + S_HLOSS];
        float th = 0.f;
        float cnt = ws[SC_OFF + S_THCNT];
        if (ws[SC_OFF + S_BAD] == 0.f && cnt > 0.f) th = ws[SC_OFF + S_THSUM] / cnt;
        out0[0] = 1.0f * bu + 1.0f * h + 3.0f * th;
    }
}

extern "C" void kernel_launch(void* const* d_in, const int* in_sizes, int n_in,
                              void* d_out, int out_size, void* d_ws, size_t ws_size,
                              hipStream_t stream) {
    const float* in = (const float*)d_in[0];
    const float* V = (const float*)d_in[1];
    const int* tgt = (const int*)d_in[2];
    float* outp = (float*)d_out;
    float* ws = (float*)d_ws;
    float* At = ws + AT_OFF;
    float* nsims = ws + NS_OFF;
    float* vrow = ws + VR_OFF;

    hipMemsetAsync(d_out, 0, (size_t)(1 + B_ * C_) * sizeof(float), stream);
    hipMemsetAsync((void*)(ws + NS_OFF), 0,
                   (size_t)(WS_FLOATS_TOTAL - NS_OFF) * sizeof(float), stream);

    build_At<<<(D_ + 255) / 256, 256, 0, stream>>>(in, V, tgt, At);
    sims_dots<<<4, 256, 0, stream>>>(in, ws + DT_OFF);
    small_finish<<<1, 1024, 0, stream>>>(in, V, tgt, ws);

    dim3 g2((C_ + 255) / 256, KSPLIT);
    gemm_lds<<<g2, 256, 0, stream>>>(At, V, outp + 1, nsims, vrow);

    row_lse<<<B_, 1024, 0, stream>>>(outp + 1, tgt, ws);

    dim3 g4((C_ + 255) / 256, B_);
    th_reduce<<<g4, 256, 0, stream>>>(nsims, ws);
    vrow_check<<<(C_ + 255) / 256, 256, 0, stream>>>(vrow, ws);
    finalize<<<1, 64, 0, stream>>>(ws, outp);
}

// Round 3
// 536.416 us; speedup vs baseline: 1.5287x; 1.1519x over previous
//
#include <hip/hip_runtime.h>
#include <math.h>

#define B_ 32
#define C_ 40000
#define D_ 2048
#define T_SCALE 10.0f
#define P_MARG 0.2f
#define N_MARG 0.3f
#define KSPLIT 8
#define KCH (D_ / KSPLIT) // 256
#define SUB 16            // k-subchunk staged in LDS

// ---- workspace layout (in floats) ----
#define AT_OFF 0
#define AT_FLOATS (D_ * 64) // A^T [2048][64]
#define NS_OFF AT_FLOATS    // nsims [32][C]
#define NS_FLOATS (B_ * C_)
#define VR_OFF (NS_OFF + NS_FLOATS) // vrow [C]
#define VR_FLOATS C_
#define SC_OFF (VR_OFF + VR_FLOATS) // scalars
#define S_HLOSS 0
#define S_THSUM 1
#define S_THCNT 2
#define S_BAD 3
#define S_NTH 4  // 32 floats
#define S_BU 36  // 32 floats
#define SC_FLOATS 128
#define DT_OFF (SC_OFF + SC_FLOATS) // raw batch dots [32][32]
#define DT_FLOATS (32 * 32)
#define WS_FLOATS_TOTAL (DT_OFF + DT_FLOATS)

__device__ __forceinline__ float softplus_f(float x) {
    return (x > 0.f) ? (x + log1pf(expf(-x))) : log1pf(expf(x));
}

// ---- K1a: At[k][a] = a<32 ? inputs[a][k] : V[targets[a-32]][k] ----
__global__ __launch_bounds__(256) void build_At(const float* __restrict__ in,
                                                const float* __restrict__ V,
                                                const int* __restrict__ tgt,
                                                float* __restrict__ At) {
    int k = blockIdx.x * 256 + threadIdx.x;
    if (k >= D_) return;
#pragma unroll
    for (int a = 0; a < 32; ++a) At[(size_t)k * 64 + a] = in[(size_t)a * D_ + k];
    for (int a = 0; a < 32; ++a) {
        int t = tgt[a];
        At[(size_t)k * 64 + 32 + a] = V[(size_t)t * D_ + k];
    }
}

// ---- K1b: raw 32x32 batch dots, one block per i, k-sliced ----
__global__ __launch_bounds__(256) void sims_dots(const float* __restrict__ in,
                                                 float* __restrict__ dt) {
    __shared__ float part[8][32];
    int i = blockIdx.x;
    int j = threadIdx.x & 31;
    int sl = threadIdx.x >> 5; // 0..7
    const float4* a4 = (const float4*)(in + (size_t)i * D_ + sl * 256);
    const float4* b4 = (const float4*)(in + (size_t)j * D_ + sl * 256);
    float s = 0.f;
#pragma unroll 4
    for (int k = 0; k < 64; ++k) {
        float4 x = a4[k], y = b4[k];
        s += x.x * y.x + x.y * y.y + x.z * y.z + x.w * y.w;
    }
    part[sl][j] = s;
    __syncthreads();
    if (threadIdx.x < 32) {
        float t = 0.f;
#pragma unroll
        for (int p = 0; p < 8; ++p) t += part[p][threadIdx.x];
        dt[i * 32 + threadIdx.x] = t;
    }
}

// ---- K1c: sims, thresholds, h_loss, n_th_t ----
__global__ __launch_bounds__(1024) void small_finish(const float* __restrict__ in,
                                                     const float* __restrict__ V,
                                                     const int* __restrict__ tgt,
                                                     float* __restrict__ ws) {
    __shared__ float sims[32][33];
    __shared__ float nthr[32], pthr[32];
    __shared__ int ts[32];
    __shared__ float diag[32];
    __shared__ float red[4];
    int tid = threadIdx.x;
    int i = tid >> 5, j = tid & 31;
    const float* dt = ws + DT_OFF;
    if (tid < 32) { ts[tid] = tgt[tid]; diag[tid] = dt[tid * 32 + tid]; }
    if (tid < 4) red[tid] = 0.f;
    __syncthreads();
    float sim = dt[i * 32 + j] * rsqrtf(diag[i] * diag[j]);
    sims[i][j] = sim;
    __syncthreads();
    if (tid < 32) {
        float nmin = 2.f, pmax = -2.f;
        int ti = ts[tid];
        for (int jj = 0; jj < 32; ++jj) {
            bool pos = (ts[jj] == ti) && (jj != tid);
            float v = sims[tid][jj];
            if (pos) { nmin = fminf(nmin, v); pmax = fmaxf(pmax, v); }
        }
        nthr[tid] = nmin - N_MARG;
        pthr[tid] = pmax - P_MARG;
    }
    __syncthreads();
    bool pos = (ts[i] == ts[j]) && (i != j);
    bool neg = (ts[i] != ts[j]);
    if (pos && sim < pthr[i]) { atomicAdd(&red[0], softplus_f(-sim)); atomicAdd(&red[1], 1.f); }
    if (neg && sim > nthr[i]) { atomicAdd(&red[2], softplus_f(sim)); atomicAdd(&red[3], 1.f); }

    // n_th_t: group i (32 lanes) computes dot(in[i], V[ts[i]])
    const float4* a4 = (const float4*)(in + (size_t)i * D_);
    const float4* v4 = (const float4*)(V + (size_t)ts[i] * D_);
    float sn = 0.f;
    for (int k = j; k < D_ / 4; k += 32) {
        float4 x = a4[k], y = v4[k];
        sn += x.x * y.x + x.y * y.y + x.z * y.z + x.w * y.w;
    }
    for (int off = 16; off > 0; off >>= 1) sn += __shfl_down(sn, off, 32);
    if (j == 0) ws[SC_OFF + S_NTH + i] = sn * rsqrtf(diag[i]) - N_MARG;
    __syncthreads();
    if (tid == 0) {
        float h = 0.f;
        if (red[1] > 0.f) h += red[0] / red[1];
        if (red[3] > 0.f) h += red[2] / red[3];
        ws[SC_OFF + S_HLOSS] = h;
    }
}

// ---- K2: register-tiled fused GEMM: both operands in LDS ----
// block = 256 cols x 64 A-rows, K-chunked; wave ty owns 16 A-rows; lane tx owns 4 cols
__global__ __launch_bounds__(256) void gemm_tile(const float* __restrict__ At,
                                                 const float* __restrict__ V,
                                                 float* __restrict__ out,   // [32][C] zeroed
                                                 float* __restrict__ nsims, // [32][C] zeroed
                                                 float* __restrict__ vrow)  // [C] zeroed
{
    __shared__ float lv[SUB][260]; // [k][col] transposed V tile, pad to 260
    __shared__ float la[SUB][64];  // [k][arow]
    const int tid = threadIdx.x;
    const int tx = tid & 63;  // col group (4 cols)
    const int ty = tid >> 6;  // wave = A-row group (16 rows)
    const int c0 = blockIdx.x * 256;
    const int k0 = blockIdx.y * KCH;

    float acc[16][4];
#pragma unroll
    for (int m = 0; m < 16; ++m)
#pragma unroll
        for (int q = 0; q < 4; ++q) acc[m][q] = 0.f;
    float vs[4] = {0.f, 0.f, 0.f, 0.f};

    const int srow = tid >> 2;        // 0..63 (V-tile col index per pass)
    const int soff = (tid & 3) * 4;   // k offset within SUB
    const int akk = tid >> 4;         // 0..15
    const int aoff = (tid & 15) * 4;  // 0..60

    for (int s = 0; s < KCH / SUB; ++s) {
        const int ks = k0 + s * SUB;
        __syncthreads();
#pragma unroll
        for (int p = 0; p < 4; ++p) {
            int row = p * 64 + srow;
            int gr = c0 + row;
            float4 v = make_float4(0.f, 0.f, 0.f, 0.f);
            if (gr < C_) v = *(const float4*)(V + (size_t)gr * D_ + ks + soff);
            lv[soff + 0][row] = v.x;
            lv[soff + 1][row] = v.y;
            lv[soff + 2][row] = v.z;
            lv[soff + 3][row] = v.w;
        }
        *(float4*)&la[akk][aoff] = *(const float4*)(At + (size_t)(ks + akk) * 64 + aoff);
        __syncthreads();
#pragma unroll
        for (int kk = 0; kk < SUB; ++kk) {
            float4 vf = *(const float4*)&lv[kk][tx * 4];
            const float4* ap4 = (const float4*)&la[kk][ty * 16];
            float4 a0 = ap4[0], a1 = ap4[1], a2 = ap4[2], a3 = ap4[3];
            if (ty == 0) { vs[0] += vf.x; vs[1] += vf.y; vs[2] += vf.z; vs[3] += vf.w; }
            float am[16] = {a0.x, a0.y, a0.z, a0.w, a1.x, a1.y, a1.z, a1.w,
                            a2.x, a2.y, a2.z, a2.w, a3.x, a3.y, a3.z, a3.w};
#pragma unroll
            for (int m = 0; m < 16; ++m) {
                acc[m][0] = fmaf(am[m], vf.x, acc[m][0]);
                acc[m][1] = fmaf(am[m], vf.y, acc[m][1]);
                acc[m][2] = fmaf(am[m], vf.z, acc[m][2]);
                acc[m][3] = fmaf(am[m], vf.w, acc[m][3]);
            }
        }
    }

    const int cbase = c0 + tx * 4;
    if (ty < 2) {
#pragma unroll
        for (int m = 0; m < 16; ++m) {
            int arow = ty * 16 + m;
#pragma unroll
            for (int q = 0; q < 4; ++q) {
                int c = cbase + q;
                if (c < C_) atomicAdd(&out[(size_t)arow * C_ + c], acc[m][q] * T_SCALE);
            }
        }
        if (ty == 0) {
#pragma unroll
            for (int q = 0; q < 4; ++q) {
                int c = cbase + q;
                if (c < C_) atomicAdd(&vrow[c], vs[q]);
            }
        }
    } else {
#pragma unroll
        for (int m = 0; m < 16; ++m) {
            int arow = (ty - 2) * 16 + m;
#pragma unroll
            for (int q = 0; q < 4; ++q) {
                int c = cbase + q;
                if (c < C_) atomicAdd(&nsims[(size_t)arow * C_ + c], acc[m][q]);
            }
        }
    }
}

// ---- K3: per-row logsumexp of outputs ----
__global__ __launch_bounds__(1024) void row_lse(const float* __restrict__ out,
                                                const int* __restrict__ tgt,
                                                float* __restrict__ ws) {
    int b = blockIdx.x;
    const float* row = out + (size_t)b * C_;
    __shared__ float sm[1024];
    int tid = threadIdx.x;
    float m = -INFINITY;
    for (int cc = tid; cc < C_; cc += 1024) m = fmaxf(m, row[cc]);
    sm[tid] = m;
    __syncthreads();
    for (int s2 = 512; s2 > 0; s2 >>= 1) {
        if (tid < s2) sm[tid] = fmaxf(sm[tid], sm[tid + s2]);
        __syncthreads();
    }
    float rmax = sm[0];
    __syncthreads();
    float s = 0.f;
    for (int cc = tid; cc < C_; cc += 1024) s += expf(row[cc] - rmax);
    sm[tid] = s;
    __syncthreads();
    for (int s2 = 512; s2 > 0; s2 >>= 1) {
        if (tid < s2) sm[tid] += sm[tid + s2];
        __syncthreads();
    }
    if (tid == 0) {
        float lse = rmax + logf(sm[0]);
        ws[SC_OFF + S_BU + b] = lse - row[tgt[b]];
    }
}

// ---- K4: th_loss masked sum over nsims ----
__global__ __launch_bounds__(256) void th_reduce(const float* __restrict__ nsims,
                                                 float* __restrict__ ws) {
    int b = blockIdx.y;
    int c = blockIdx.x * 256 + threadIdx.x;
    int tid = threadIdx.x;
    float nth = ws[SC_OFF + S_NTH + b];
    float sum = 0.f, cnt = 0.f;
    if (c < C_) {
        float x = nsims[(size_t)b * C_ + c];
        if (x > nth && x < 0.9999f) { sum = softplus_f(x); cnt = 1.f; }
    }
    __shared__ float ssum[256];
    __shared__ float scnt[256];
    ssum[tid] = sum;
    scnt[tid] = cnt;
    __syncthreads();
    for (int s2 = 128; s2 > 0; s2 >>= 1) {
        if (tid < s2) { ssum[tid] += ssum[tid + s2]; scnt[tid] += scnt[tid + s2]; }
        __syncthreads();
    }
    if (tid == 0 && scnt[0] != 0.f) {
        atomicAdd(&ws[SC_OFF + S_THSUM], ssum[0]);
        atomicAdd(&ws[SC_OFF + S_THCNT], scnt[0]);
    }
}

// ---- K4b: active-flag (any zero V row-sum) ----
__global__ __launch_bounds__(256) void vrow_check(const float* __restrict__ vrow,
                                                  float* __restrict__ ws) {
    int c = blockIdx.x * 256 + threadIdx.x;
    if (c < C_ && vrow[c] == 0.0f) ws[SC_OFF + S_BAD] = 1.0f;
}

// ---- K5: combine ----
__global__ void finalize(const float* __restrict__ ws, float* __restrict__ out0) {
    if (threadIdx.x == 0 && blockIdx.x == 0) {
        float bu = 0.f;
        for (int b = 0; b < 32; ++b) bu += ws[SC_OFF + S_BU + b];
        bu /= 32.f;
        float h = ws[SC_OFF + S_HLOSS];
        float th = 0.f;
        float cnt = ws[SC_OFF + S_THCNT];
        if (ws[SC_OFF + S_BAD] == 0.f && cnt > 0.f) th = ws[SC_OFF + S_THSUM] / cnt;
        out0[0] = 1.0f * bu + 1.0f * h + 3.0f * th;
    }
}

extern "C" void kernel_launch(void* const* d_in, const int* in_sizes, int n_in,
                              void* d_out, int out_size, void* d_ws, size_t ws_size,
                              hipStream_t stream) {
    const float* in = (const float*)d_in[0];
    const float* V = (const float*)d_in[1];
    const int* tgt = (const int*)d_in[2];
    float* outp = (float*)d_out;
    float* ws = (float*)d_ws;
    float* At = ws + AT_OFF;
    float* nsims = ws + NS_OFF;
    float* vrow = ws + VR_OFF;

    hipMemsetAsync(d_out, 0, (size_t)(1 + B_ * C_) * sizeof(float), stream);
    hipMemsetAsync((void*)(ws + NS_OFF), 0,
                   (size_t)(DT_OFF - NS_OFF) * sizeof(float), stream);

    build_At<<<(D_ + 255) / 256, 256, 0, stream>>>(in, V, tgt, At);
    sims_dots<<<32, 256, 0, stream>>>(in, ws + DT_OFF);
    small_finish<<<1, 1024, 0, stream>>>(in, V, tgt, ws);

    dim3 g2((C_ + 255) / 256, KSPLIT);
    gemm_tile<<<g2, 256, 0, stream>>>(At, V, outp + 1, nsims, vrow);

    row_lse<<<B_, 1024, 0, stream>>>(outp + 1, tgt, ws);

    dim3 g4((C_ + 255) / 256, B_);
    th_reduce<<<g4, 256, 0, stream>>>(nsims, ws);
    vrow_check<<<(C_ + 255) / 256, 256, 0, stream>>>(vrow, ws);
    finalize<<<1, 64, 0, stream>>>(ws, outp);
}

// Round 4
// 474.377 us; speedup vs baseline: 1.7286x; 1.1308x over previous
//
#include <hip/hip_runtime.h>
#include <math.h>

#define B_ 32
#define C_ 40000
#define D_ 2048
#define T_SCALE 10.0f
#define P_MARG 0.2f
#define N_MARG 0.3f
#define NWAVES (C_ / 16) // 2500

typedef __attribute__((ext_vector_type(4))) float f32x4;
typedef __attribute__((ext_vector_type(8))) short short8_t;

// ---- workspace layout (in floats) ----
#define PM_OFF 0                      // pmax [32][NWAVES]
#define PM_FLOATS (B_ * NWAVES)
#define PS_OFF (PM_OFF + PM_FLOATS)   // psum [32][NWAVES]
#define PS_FLOATS (B_ * NWAVES)
#define SC_OFF (PS_OFF + PS_FLOATS)   // scalars
#define S_HLOSS 0
#define S_THSUM 1
#define S_THCNT 2
#define S_BAD 3
#define S_NTH 4  // 32 floats
#define S_BU 36  // 32 floats
#define SC_FLOATS 128
#define DT_OFF (SC_OFF + SC_FLOATS)   // raw batch dots [32][32]
#define DT_FLOATS (32 * 32)
#define AH_OFF (DT_OFF + DT_FLOATS)   // A_hi bf16 [64][2048] as ushort (65536 floats)
#define AH_FLOATS (64 * D_ / 2)
#define AL_OFF (AH_OFF + AH_FLOATS)   // A_lo bf16
#define AL_FLOATS (64 * D_ / 2)
#define WS_FLOATS_TOTAL (AL_OFF + AL_FLOATS)

__device__ __forceinline__ float softplus_f(float x) {
    return (x > 0.f) ? (x + log1pf(expf(-x))) : log1pf(expf(x));
}

// split x into hi(bf16 trunc) + lo(bf16 trunc of remainder); pack 2 elems per uint
__device__ __forceinline__ void split2(float x0, float x1, unsigned& uh, unsigned& ul) {
    unsigned b0 = __float_as_uint(x0), b1 = __float_as_uint(x1);
    uh = (b0 >> 16) | (b1 & 0xFFFF0000u);
    float h0 = __uint_as_float(b0 & 0xFFFF0000u);
    float h1 = __uint_as_float(b1 & 0xFFFF0000u);
    unsigned l0 = __float_as_uint(x0 - h0), l1 = __float_as_uint(x1 - h1);
    ul = (l0 >> 16) | (l1 & 0xFFFF0000u);
}

// ---- K0: pre-split A (rows 0-31 = inputs, 32-63 = V[tgt]) into bf16 hi/lo ----
__global__ __launch_bounds__(256) void build_Ahl(const float* __restrict__ in,
                                                 const float* __restrict__ V,
                                                 const int* __restrict__ tgt,
                                                 unsigned short* __restrict__ Ah,
                                                 unsigned short* __restrict__ Al) {
    int idx = blockIdx.x * 256 + threadIdx.x;
    int e0 = idx * 4;
    if (e0 >= 64 * D_) return;
    int row = e0 >> 11;
    int k = e0 & (D_ - 1);
    const float* src = (row < 32) ? (in + (size_t)row * D_ + k)
                                  : (V + (size_t)tgt[row - 32] * D_ + k);
    f32x4 x = *(const f32x4*)src;
    unsigned uh0, ul0, uh1, ul1;
    split2(x[0], x[1], uh0, ul0);
    split2(x[2], x[3], uh1, ul1);
    *(uint2*)(Ah + e0) = make_uint2(uh0, uh1);
    *(uint2*)(Al + e0) = make_uint2(ul0, ul1);
}

// ---- K1b: raw 32x32 batch dots ----
__global__ __launch_bounds__(256) void sims_dots(const float* __restrict__ in,
                                                 float* __restrict__ dt) {
    __shared__ float part[8][32];
    int i = blockIdx.x;
    int j = threadIdx.x & 31;
    int sl = threadIdx.x >> 5;
    const float4* a4 = (const float4*)(in + (size_t)i * D_ + sl * 256);
    const float4* b4 = (const float4*)(in + (size_t)j * D_ + sl * 256);
    float s = 0.f;
#pragma unroll 4
    for (int k = 0; k < 64; ++k) {
        float4 x = a4[k], y = b4[k];
        s += x.x * y.x + x.y * y.y + x.z * y.z + x.w * y.w;
    }
    part[sl][j] = s;
    __syncthreads();
    if (threadIdx.x < 32) {
        float t = 0.f;
#pragma unroll
        for (int p = 0; p < 8; ++p) t += part[p][threadIdx.x];
        dt[i * 32 + threadIdx.x] = t;
    }
}

// ---- K1c: sims, thresholds, h_loss, n_th_t ----
__global__ __launch_bounds__(1024) void small_finish(const float* __restrict__ in,
                                                     const float* __restrict__ V,
                                                     const int* __restrict__ tgt,
                                                     float* __restrict__ ws) {
    __shared__ float sims[32][33];
    __shared__ float nthr[32], pthr[32];
    __shared__ int ts[32];
    __shared__ float diag[32];
    __shared__ float red[4];
    int tid = threadIdx.x;
    int i = tid >> 5, j = tid & 31;
    const float* dt = ws + DT_OFF;
    if (tid < 32) { ts[tid] = tgt[tid]; diag[tid] = dt[tid * 32 + tid]; }
    if (tid < 4) red[tid] = 0.f;
    __syncthreads();
    float sim = dt[i * 32 + j] * rsqrtf(diag[i] * diag[j]);
    sims[i][j] = sim;
    __syncthreads();
    if (tid < 32) {
        float nmin = 2.f, pmax = -2.f;
        int ti = ts[tid];
        for (int jj = 0; jj < 32; ++jj) {
            bool pos = (ts[jj] == ti) && (jj != tid);
            float v = sims[tid][jj];
            if (pos) { nmin = fminf(nmin, v); pmax = fmaxf(pmax, v); }
        }
        nthr[tid] = nmin - N_MARG;
        pthr[tid] = pmax - P_MARG;
    }
    __syncthreads();
    bool pos = (ts[i] == ts[j]) && (i != j);
    bool neg = (ts[i] != ts[j]);
    if (pos && sim < pthr[i]) { atomicAdd(&red[0], softplus_f(-sim)); atomicAdd(&red[1], 1.f); }
    if (neg && sim > nthr[i]) { atomicAdd(&red[2], softplus_f(sim)); atomicAdd(&red[3], 1.f); }

    const float4* a4 = (const float4*)(in + (size_t)i * D_);
    const float4* v4 = (const float4*)(V + (size_t)ts[i] * D_);
    float sn = 0.f;
    for (int k = j; k < D_ / 4; k += 32) {
        float4 x = a4[k], y = v4[k];
        sn += x.x * y.x + x.y * y.y + x.z * y.z + x.w * y.w;
    }
    for (int off = 16; off > 0; off >>= 1) sn += __shfl_down(sn, off, 32);
    if (j == 0) ws[SC_OFF + S_NTH + i] = sn * rsqrtf(diag[i]) - N_MARG;
    __syncthreads();
    if (tid == 0) {
        float h = 0.f;
        if (red[1] > 0.f) h += red[0] / red[1];
        if (red[3] > 0.f) h += red[2] / red[3];
        ws[SC_OFF + S_HLOSS] = h;
    }
}

// ---- epilogue helpers for gemm ----
__device__ __forceinline__ void out_tile(f32x4 a, int rowbase, int g, int col, int n0,
                                         int wid, float* __restrict__ out,
                                         float* __restrict__ ws) {
#pragma unroll
    for (int r = 0; r < 4; ++r) {
        int row = rowbase + g * 4 + r;
        float y = a[r] * T_SCALE;
        out[(size_t)row * C_ + n0 + col] = y;
        float gm = y;
        gm = fmaxf(gm, __shfl_xor(gm, 1));
        gm = fmaxf(gm, __shfl_xor(gm, 2));
        gm = fmaxf(gm, __shfl_xor(gm, 4));
        gm = fmaxf(gm, __shfl_xor(gm, 8));
        float es = expf(y - gm);
        es += __shfl_xor(es, 1);
        es += __shfl_xor(es, 2);
        es += __shfl_xor(es, 4);
        es += __shfl_xor(es, 8);
        if (col == 0) {
            ws[PM_OFF + (size_t)row * NWAVES + wid] = gm;
            ws[PS_OFF + (size_t)row * NWAVES + wid] = es;
        }
    }
}

__device__ __forceinline__ void th_tile(f32x4 a, int bbase, int g, const float* __restrict__ nthp,
                                        float& ts, float& tc) {
#pragma unroll
    for (int r = 0; r < 4; ++r) {
        int b = bbase + g * 4 + r;
        float x = a[r];
        float nth = nthp[b];
        if (x > nth && x < 0.9999f) { ts += softplus_f(x); tc += 1.f; }
    }
}

// ---- K2: MFMA GEMM, 1 wave = 16 V-rows (cols), full K, fused epilogues ----
__global__ __launch_bounds__(64) void gemm_mfma(const float* __restrict__ V,
                                                const unsigned short* __restrict__ Ah,
                                                const unsigned short* __restrict__ Al,
                                                float* __restrict__ out,
                                                float* __restrict__ ws) {
    const int wid = blockIdx.x;
    const int l = threadIdx.x;
    const int col = l & 15, g = l >> 4;
    const int n0 = wid * 16;
    const float* vp = V + (size_t)(n0 + col) * D_ + g * 8;
    const unsigned short* ahp = Ah + (size_t)col * D_ + g * 8;
    const unsigned short* alp = Al + (size_t)col * D_ + g * 8;

    f32x4 acc0 = {0.f, 0.f, 0.f, 0.f};
    f32x4 acc1 = acc0, acc2 = acc0, acc3 = acc0;
    float vsum = 0.f;

    f32x4 v0 = *(const f32x4*)(vp);
    f32x4 v1 = *(const f32x4*)(vp + 4);
    for (int k0 = 0; k0 < D_; k0 += 32) {
        f32x4 nv0, nv1;
        const bool more = (k0 + 32) < D_;
        if (more) {
            nv0 = *(const f32x4*)(vp + k0 + 32);
            nv1 = *(const f32x4*)(vp + k0 + 36);
        }
        // A fragments (L2-resident)
        uint4 ah0 = *(const uint4*)(ahp + 0 * 16 * D_ + k0);
        uint4 ah1 = *(const uint4*)(ahp + 1 * 16 * D_ + k0);
        uint4 ah2 = *(const uint4*)(ahp + 2 * 16 * D_ + k0);
        uint4 ah3 = *(const uint4*)(ahp + 3 * 16 * D_ + k0);
        uint4 al0 = *(const uint4*)(alp + 0 * 16 * D_ + k0);
        uint4 al1 = *(const uint4*)(alp + 1 * 16 * D_ + k0);
        uint4 al2 = *(const uint4*)(alp + 2 * 16 * D_ + k0);
        uint4 al3 = *(const uint4*)(alp + 3 * 16 * D_ + k0);

        vsum += v0[0] + v0[1] + v0[2] + v0[3] + v1[0] + v1[1] + v1[2] + v1[3];
        unsigned uh0, ul0, uh1, ul1, uh2, ul2, uh3, ul3;
        split2(v0[0], v0[1], uh0, ul0);
        split2(v0[2], v0[3], uh1, ul1);
        split2(v1[0], v1[1], uh2, ul2);
        split2(v1[2], v1[3], uh3, ul3);
        uint4 bhu = make_uint4(uh0, uh1, uh2, uh3);
        uint4 blu = make_uint4(ul0, ul1, ul2, ul3);
        short8_t bhi = __builtin_bit_cast(short8_t, bhu);
        short8_t blo = __builtin_bit_cast(short8_t, blu);

        short8_t a0h = __builtin_bit_cast(short8_t, ah0);
        short8_t a1h = __builtin_bit_cast(short8_t, ah1);
        short8_t a2h = __builtin_bit_cast(short8_t, ah2);
        short8_t a3h = __builtin_bit_cast(short8_t, ah3);
        short8_t a0l = __builtin_bit_cast(short8_t, al0);
        short8_t a1l = __builtin_bit_cast(short8_t, al1);
        short8_t a2l = __builtin_bit_cast(short8_t, al2);
        short8_t a3l = __builtin_bit_cast(short8_t, al3);

        acc0 = __builtin_amdgcn_mfma_f32_16x16x32_bf16(a0h, bhi, acc0, 0, 0, 0);
        acc1 = __builtin_amdgcn_mfma_f32_16x16x32_bf16(a1h, bhi, acc1, 0, 0, 0);
        acc2 = __builtin_amdgcn_mfma_f32_16x16x32_bf16(a2h, bhi, acc2, 0, 0, 0);
        acc3 = __builtin_amdgcn_mfma_f32_16x16x32_bf16(a3h, bhi, acc3, 0, 0, 0);
        acc0 = __builtin_amdgcn_mfma_f32_16x16x32_bf16(a0h, blo, acc0, 0, 0, 0);
        acc1 = __builtin_amdgcn_mfma_f32_16x16x32_bf16(a1h, blo, acc1, 0, 0, 0);
        acc2 = __builtin_amdgcn_mfma_f32_16x16x32_bf16(a2h, blo, acc2, 0, 0, 0);
        acc3 = __builtin_amdgcn_mfma_f32_16x16x32_bf16(a3h, blo, acc3, 0, 0, 0);
        acc0 = __builtin_amdgcn_mfma_f32_16x16x32_bf16(a0l, bhi, acc0, 0, 0, 0);
        acc1 = __builtin_amdgcn_mfma_f32_16x16x32_bf16(a1l, bhi, acc1, 0, 0, 0);
        acc2 = __builtin_amdgcn_mfma_f32_16x16x32_bf16(a2l, bhi, acc2, 0, 0, 0);
        acc3 = __builtin_amdgcn_mfma_f32_16x16x32_bf16(a3l, bhi, acc3, 0, 0, 0);

        if (more) { v0 = nv0; v1 = nv1; }
    }

    // V row-sum zero check (rows n0+col)
    vsum += __shfl_xor(vsum, 16);
    vsum += __shfl_xor(vsum, 32);
    if (g == 0 && vsum == 0.0f) ws[SC_OFF + S_BAD] = 1.0f;

    // outputs rows 0..31 (+ lse partials)
    out_tile(acc0, 0, g, col, n0, wid, out, ws);
    out_tile(acc1, 16, g, col, n0, wid, out, ws);

    // th rows 0..31 from nsims accumulators
    float ts = 0.f, tc = 0.f;
    const float* nthp = ws + SC_OFF + S_NTH;
    th_tile(acc2, 0, g, nthp, ts, tc);
    th_tile(acc3, 16, g, nthp, ts, tc);
#pragma unroll
    for (int off = 32; off >= 1; off >>= 1) {
        ts += __shfl_xor(ts, off);
        tc += __shfl_xor(tc, off);
    }
    if (l == 0 && tc != 0.f) {
        atomicAdd(&ws[SC_OFF + S_THSUM], ts);
        atomicAdd(&ws[SC_OFF + S_THCNT], tc);
    }
}

// ---- K3: combine lse partials, bu term ----
__global__ __launch_bounds__(256) void lse_combine(const float* __restrict__ out,
                                                   const int* __restrict__ tgt,
                                                   float* __restrict__ ws) {
    int b = blockIdx.x;
    int tid = threadIdx.x;
    __shared__ float sm[256];
    const float* pm = ws + PM_OFF + (size_t)b * NWAVES;
    const float* ps = ws + PS_OFF + (size_t)b * NWAVES;
    float m = -INFINITY;
    for (int i = tid; i < NWAVES; i += 256) m = fmaxf(m, pm[i]);
    sm[tid] = m;
    __syncthreads();
    for (int s = 128; s > 0; s >>= 1) {
        if (tid < s) sm[tid] = fmaxf(sm[tid], sm[tid + s]);
        __syncthreads();
    }
    float M = sm[0];
    __syncthreads();
    float s = 0.f;
    for (int i = tid; i < NWAVES; i += 256) s += ps[i] * expf(pm[i] - M);
    sm[tid] = s;
    __syncthreads();
    for (int st = 128; st > 0; st >>= 1) {
        if (tid < st) sm[tid] += sm[tid + st];
        __syncthreads();
    }
    if (tid == 0) {
        float lse = M + logf(sm[0]);
        ws[SC_OFF + S_BU + b] = lse - out[(size_t)b * C_ + tgt[b]];
    }
}

// ---- K5: combine ----
__global__ void finalize(const float* __restrict__ ws, float* __restrict__ out0) {
    if (threadIdx.x == 0 && blockIdx.x == 0) {
        float bu = 0.f;
        for (int b = 0; b < 32; ++b) bu += ws[SC_OFF + S_BU + b];
        bu /= 32.f;
        float h = ws[SC_OFF + S_HLOSS];
        float th = 0.f;
        float cnt = ws[SC_OFF + S_THCNT];
        if (ws[SC_OFF + S_BAD] == 0.f && cnt > 0.f) th = ws[SC_OFF + S_THSUM] / cnt;
        out0[0] = 1.0f * bu + 1.0f * h + 3.0f * th;
    }
}

extern "C" void kernel_launch(void* const* d_in, const int* in_sizes, int n_in,
                              void* d_out, int out_size, void* d_ws, size_t ws_size,
                              hipStream_t stream) {
    const float* in = (const float*)d_in[0];
    const float* V = (const float*)d_in[1];
    const int* tgt = (const int*)d_in[2];
    float* outp = (float*)d_out;
    float* ws = (float*)d_ws;
    unsigned short* Ah = (unsigned short*)(ws + AH_OFF);
    unsigned short* Al = (unsigned short*)(ws + AL_OFF);

    hipMemsetAsync((void*)(ws + SC_OFF), 0, SC_FLOATS * sizeof(float), stream);

    build_Ahl<<<(64 * D_ / 4 + 255) / 256, 256, 0, stream>>>(in, V, tgt, Ah, Al);
    sims_dots<<<32, 256, 0, stream>>>(in, ws + DT_OFF);
    small_finish<<<1, 1024, 0, stream>>>(in, V, tgt, ws);

    gemm_mfma<<<NWAVES, 64, 0, stream>>>(V, Ah, Al, outp + 1, ws);

    lse_combine<<<B_, 256, 0, stream>>>(outp + 1, tgt, ws);
    finalize<<<1, 64, 0, stream>>>(ws, outp);
}

// Round 6
// 317.155 us; speedup vs baseline: 2.5855x; 1.4957x over previous
//
#include <hip/hip_runtime.h>
#include <math.h>

#define B_ 32
#define C_ 40000
#define D_ 2048
#define T_SCALE 10.0f
#define P_MARG 0.2f
#define N_MARG 0.3f
#define NWAVES (C_ / 16) // 2500
#define NSTEP (D_ / 32)  // 64

typedef __attribute__((ext_vector_type(4))) float f32x4;
typedef __fp16 fp16x2 __attribute__((ext_vector_type(2)));
typedef _Float16 half8_t __attribute__((ext_vector_type(8)));

// ---- workspace layout (in floats) ----
#define PM_OFF 0                      // pmax [32][NWAVES]
#define PM_FLOATS (B_ * NWAVES)
#define PS_OFF (PM_OFF + PM_FLOATS)   // psum [32][NWAVES]
#define PS_FLOATS (B_ * NWAVES)
#define SC_OFF (PS_OFF + PS_FLOATS)   // scalars
#define S_HLOSS 0
#define S_THSUM 1
#define S_THCNT 2
#define S_BAD 3
#define S_NTH 4  // 32 floats
#define S_BU 36  // 32 floats
#define SC_FLOATS 128
#define DT_OFF (SC_OFF + SC_FLOATS)   // raw batch dots [32][32]
#define DT_FLOATS (32 * 32)
#define AF_OFF (DT_OFF + DT_FLOATS)   // A fragments: 64 steps * 8 frags * 64 lanes * 8 f16
#define AF_FLOATS (NSTEP * 4096 / 2)  // 131072 floats = 512KB
#define WS_FLOATS_TOTAL (AF_OFF + AF_FLOATS)

__device__ __forceinline__ float softplus_f(float x) {
    return (x > 0.f) ? (x + log1pf(expf(-x))) : log1pf(expf(x));
}

// split (x0,x1) into packed f16 hi (RTZ) + f16 lo (RTZ of remainder)
__device__ __forceinline__ void split_f16x2(float x0, float x1, unsigned& uh, unsigned& ul) {
    fp16x2 h = __builtin_amdgcn_cvt_pkrtz(x0, x1);
    float r0 = x0 - (float)h[0];
    float r1 = x1 - (float)h[1];
    fp16x2 lo = __builtin_amdgcn_cvt_pkrtz(r0, r1);
    uh = __builtin_bit_cast(unsigned, h);
    ul = __builtin_bit_cast(unsigned, lo);
}

// ---- K0: pack A (rows 0-31 = inputs, 32-63 = V[tgt]) into fragment-major f16 hi/lo ----
// layout (ushort idx): s*4096 + f*512 + lane*8 + j ; f = rb (hi) or 4+rb (lo)
__global__ __launch_bounds__(256) void build_Afrag(const float* __restrict__ in,
                                                   const float* __restrict__ V,
                                                   const int* __restrict__ tgt,
                                                   unsigned short* __restrict__ Af) {
    int s = blockIdx.x;           // 0..63
    int rb = threadIdx.x >> 6;    // 0..3
    int l = threadIdx.x & 63;
    int row = rb * 16 + (l & 15);
    int k = s * 32 + (l >> 4) * 8;
    const float* src = (row < 32) ? (in + (size_t)row * D_ + k)
                                  : (V + (size_t)tgt[row - 32] * D_ + k);
    f32x4 x0 = *(const f32x4*)src;
    f32x4 x1 = *(const f32x4*)(src + 4);
    unsigned uh0, ul0, uh1, ul1, uh2, ul2, uh3, ul3;
    split_f16x2(x0[0], x0[1], uh0, ul0);
    split_f16x2(x0[2], x0[3], uh1, ul1);
    split_f16x2(x1[0], x1[1], uh2, ul2);
    split_f16x2(x1[2], x1[3], uh3, ul3);
    size_t base = (size_t)s * 4096 + (size_t)l * 8;
    *(uint4*)(Af + base + rb * 512) = make_uint4(uh0, uh1, uh2, uh3);
    *(uint4*)(Af + base + (4 + rb) * 512) = make_uint4(ul0, ul1, ul2, ul3);
}

// ---- K1b: raw 32x32 batch dots ----
__global__ __launch_bounds__(256) void sims_dots(const float* __restrict__ in,
                                                 float* __restrict__ dt) {
    __shared__ float part[8][32];
    int i = blockIdx.x;
    int j = threadIdx.x & 31;
    int sl = threadIdx.x >> 5;
    const float4* a4 = (const float4*)(in + (size_t)i * D_ + sl * 256);
    const float4* b4 = (const float4*)(in + (size_t)j * D_ + sl * 256);
    float s = 0.f;
#pragma unroll 4
    for (int k = 0; k < 64; ++k) {
        float4 x = a4[k], y = b4[k];
        s += x.x * y.x + x.y * y.y + x.z * y.z + x.w * y.w;
    }
    part[sl][j] = s;
    __syncthreads();
    if (threadIdx.x < 32) {
        float t = 0.f;
#pragma unroll
        for (int p = 0; p < 8; ++p) t += part[p][threadIdx.x];
        dt[i * 32 + threadIdx.x] = t;
    }
}

// ---- K1c: sims, thresholds, h_loss, n_th_t ----
__global__ __launch_bounds__(1024) void small_finish(const float* __restrict__ in,
                                                     const float* __restrict__ V,
                                                     const int* __restrict__ tgt,
                                                     float* __restrict__ ws) {
    __shared__ float sims[32][33];
    __shared__ float nthr[32], pthr[32];
    __shared__ int ts[32];
    __shared__ float diag[32];
    __shared__ float red[4];
    int tid = threadIdx.x;
    int i = tid >> 5, j = tid & 31;
    const float* dt = ws + DT_OFF;
    if (tid < 32) { ts[tid] = tgt[tid]; diag[tid] = dt[tid * 32 + tid]; }
    if (tid < 4) red[tid] = 0.f;
    __syncthreads();
    float sim = dt[i * 32 + j] * rsqrtf(diag[i] * diag[j]);
    sims[i][j] = sim;
    __syncthreads();
    if (tid < 32) {
        float nmin = 2.f, pmax = -2.f;
        int ti = ts[tid];
        for (int jj = 0; jj < 32; ++jj) {
            bool pos = (ts[jj] == ti) && (jj != tid);
            float v = sims[tid][jj];
            if (pos) { nmin = fminf(nmin, v); pmax = fmaxf(pmax, v); }
        }
        nthr[tid] = nmin - N_MARG;
        pthr[tid] = pmax - P_MARG;
    }
    __syncthreads();
    bool pos = (ts[i] == ts[j]) && (i != j);
    bool neg = (ts[i] != ts[j]);
    if (pos && sim < pthr[i]) { atomicAdd(&red[0], softplus_f(-sim)); atomicAdd(&red[1], 1.f); }
    if (neg && sim > nthr[i]) { atomicAdd(&red[2], softplus_f(sim)); atomicAdd(&red[3], 1.f); }

    const float4* a4 = (const float4*)(in + (size_t)i * D_);
    const float4* v4 = (const float4*)(V + (size_t)ts[i] * D_);
    float sn = 0.f;
    for (int k = j; k < D_ / 4; k += 32) {
        float4 x = a4[k], y = v4[k];
        sn += x.x * y.x + x.y * y.y + x.z * y.z + x.w * y.w;
    }
    for (int off = 16; off > 0; off >>= 1) sn += __shfl_down(sn, off, 32);
    if (j == 0) ws[SC_OFF + S_NTH + i] = sn * rsqrtf(diag[i]) - N_MARG;
    __syncthreads();
    if (tid == 0) {
        float h = 0.f;
        if (red[1] > 0.f) h += red[0] / red[1];
        if (red[3] > 0.f) h += red[2] / red[3];
        ws[SC_OFF + S_HLOSS] = h;
    }
}

// ---- epilogue helpers ----
__device__ __forceinline__ void out_tile(f32x4 a, int rowbase, int g, int col, int n0,
                                         int wid, float* __restrict__ out,
                                         float* __restrict__ ws) {
#pragma unroll
    for (int r = 0; r < 4; ++r) {
        int row = rowbase + g * 4 + r;
        float y = a[r] * T_SCALE;
        out[(size_t)row * C_ + n0 + col] = y;
        float gm = y;
        gm = fmaxf(gm, __shfl_xor(gm, 1));
        gm = fmaxf(gm, __shfl_xor(gm, 2));
        gm = fmaxf(gm, __shfl_xor(gm, 4));
        gm = fmaxf(gm, __shfl_xor(gm, 8));
        float es = expf(y - gm);
        es += __shfl_xor(es, 1);
        es += __shfl_xor(es, 2);
        es += __shfl_xor(es, 4);
        es += __shfl_xor(es, 8);
        if (col == 0) {
            ws[PM_OFF + (size_t)row * NWAVES + wid] = gm;
            ws[PS_OFF + (size_t)row * NWAVES + wid] = es;
        }
    }
}

__device__ __forceinline__ void th_tile(f32x4 a, int bbase, int g, const float* __restrict__ nthp,
                                        float& ts, float& tc) {
#pragma unroll
    for (int r = 0; r < 4; ++r) {
        int b = bbase + g * 4 + r;
        float x = a[r];
        float nth = nthp[b];
        if (x > nth && x < 0.9999f) { ts += softplus_f(x); tc += 1.f; }
    }
}

// ---- K2: MFMA GEMM, 4 independent waves/block, 16 V-rows per wave, full K,
//          1-step register prefetch of both A-frags and V, fused epilogues ----
__global__ __launch_bounds__(256) void gemm_mfma(const float* __restrict__ V,
                                                 const unsigned short* __restrict__ Af,
                                                 float* __restrict__ out,
                                                 float* __restrict__ ws) {
    const int l = threadIdx.x & 63;
    const int w = threadIdx.x >> 6;
    const int wid = blockIdx.x * 4 + w;
    const int col = l & 15, g = l >> 4;
    const int n0 = wid * 16;
    const float* vp = V + (size_t)(n0 + col) * D_ + g * 8;
    const unsigned short* afp = Af + (size_t)l * 8;

    f32x4 acc0 = {0.f, 0.f, 0.f, 0.f};
    f32x4 acc1 = acc0, acc2 = acc0, acc3 = acc0;
    float vsum = 0.f;

    uint4 a[8];
    f32x4 v0, v1;
#pragma unroll
    for (int f = 0; f < 8; ++f) a[f] = *(const uint4*)(afp + f * 512);
    v0 = *(const f32x4*)(vp);
    v1 = *(const f32x4*)(vp + 4);

    for (int s = 0; s < NSTEP; ++s) {
        uint4 na[8];
        f32x4 nv0, nv1;
        const bool more = (s + 1) < NSTEP;
        if (more) {
            const unsigned short* nap = afp + (size_t)(s + 1) * 4096;
#pragma unroll
            for (int f = 0; f < 8; ++f) na[f] = *(const uint4*)(nap + f * 512);
            nv0 = *(const f32x4*)(vp + (s + 1) * 32);
            nv1 = *(const f32x4*)(vp + (s + 1) * 32 + 4);
        }

        vsum += v0[0] + v0[1] + v0[2] + v0[3] + v1[0] + v1[1] + v1[2] + v1[3];
        unsigned uh0, ul0, uh1, ul1, uh2, ul2, uh3, ul3;
        split_f16x2(v0[0], v0[1], uh0, ul0);
        split_f16x2(v0[2], v0[3], uh1, ul1);
        split_f16x2(v1[0], v1[1], uh2, ul2);
        split_f16x2(v1[2], v1[3], uh3, ul3);
        half8_t bh = __builtin_bit_cast(half8_t, make_uint4(uh0, uh1, uh2, uh3));
        half8_t bl = __builtin_bit_cast(half8_t, make_uint4(ul0, ul1, ul2, ul3));

        half8_t a0h = __builtin_bit_cast(half8_t, a[0]);
        half8_t a1h = __builtin_bit_cast(half8_t, a[1]);
        half8_t a2h = __builtin_bit_cast(half8_t, a[2]);
        half8_t a3h = __builtin_bit_cast(half8_t, a[3]);
        half8_t a0l = __builtin_bit_cast(half8_t, a[4]);
        half8_t a1l = __builtin_bit_cast(half8_t, a[5]);
        half8_t a2l = __builtin_bit_cast(half8_t, a[6]);
        half8_t a3l = __builtin_bit_cast(half8_t, a[7]);

        acc0 = __builtin_amdgcn_mfma_f32_16x16x32_f16(a0h, bh, acc0, 0, 0, 0);
        acc1 = __builtin_amdgcn_mfma_f32_16x16x32_f16(a1h, bh, acc1, 0, 0, 0);
        acc2 = __builtin_amdgcn_mfma_f32_16x16x32_f16(a2h, bh, acc2, 0, 0, 0);
        acc3 = __builtin_amdgcn_mfma_f32_16x16x32_f16(a3h, bh, acc3, 0, 0, 0);
        acc0 = __builtin_amdgcn_mfma_f32_16x16x32_f16(a0h, bl, acc0, 0, 0, 0);
        acc1 = __builtin_amdgcn_mfma_f32_16x16x32_f16(a1h, bl, acc1, 0, 0, 0);
        acc2 = __builtin_amdgcn_mfma_f32_16x16x32_f16(a2h, bl, acc2, 0, 0, 0);
        acc3 = __builtin_amdgcn_mfma_f32_16x16x32_f16(a3h, bl, acc3, 0, 0, 0);
        acc0 = __builtin_amdgcn_mfma_f32_16x16x32_f16(a0l, bh, acc0, 0, 0, 0);
        acc1 = __builtin_amdgcn_mfma_f32_16x16x32_f16(a1l, bh, acc1, 0, 0, 0);
        acc2 = __builtin_amdgcn_mfma_f32_16x16x32_f16(a2l, bh, acc2, 0, 0, 0);
        acc3 = __builtin_amdgcn_mfma_f32_16x16x32_f16(a3l, bh, acc3, 0, 0, 0);

        if (more) {
#pragma unroll
            for (int f = 0; f < 8; ++f) a[f] = na[f];
            v0 = nv0;
            v1 = nv1;
        }
    }

    // V row-sum zero check (rows n0+col)
    vsum += __shfl_xor(vsum, 16);
    vsum += __shfl_xor(vsum, 32);
    if (g == 0 && vsum == 0.0f) ws[SC_OFF + S_BAD] = 1.0f;

    // outputs rows 0..31 (+ lse partials)
    out_tile(acc0, 0, g, col, n0, wid, out, ws);
    out_tile(acc1, 16, g, col, n0, wid, out, ws);

    // th term from nsims accumulators (rows 32..63)
    float ts = 0.f, tc = 0.f;
    const float* nthp = ws + SC_OFF + S_NTH;
    th_tile(acc2, 0, g, nthp, ts, tc);
    th_tile(acc3, 16, g, nthp, ts, tc);
#pragma unroll
    for (int off = 32; off >= 1; off >>= 1) {
        ts += __shfl_xor(ts, off);
        tc += __shfl_xor(tc, off);
    }
    if (l == 0 && tc != 0.f) {
        atomicAdd(&ws[SC_OFF + S_THSUM], ts);
        atomicAdd(&ws[SC_OFF + S_THCNT], tc);
    }
}

// ---- K3: combine lse partials, bu term ----
__global__ __launch_bounds__(256) void lse_combine(const float* __restrict__ out,
                                                   const int* __restrict__ tgt,
                                                   float* __restrict__ ws) {
    int b = blockIdx.x;
    int tid = threadIdx.x;
    __shared__ float sm[256];
    const float* pm = ws + PM_OFF + (size_t)b * NWAVES;
    const float* ps = ws + PS_OFF + (size_t)b * NWAVES;
    float m = -INFINITY;
    for (int i = tid; i < NWAVES; i += 256) m = fmaxf(m, pm[i]);
    sm[tid] = m;
    __syncthreads();
    for (int s = 128; s > 0; s >>= 1) {
        if (tid < s) sm[tid] = fmaxf(sm[tid], sm[tid + s]);
        __syncthreads();
    }
    float M = sm[0];
    __syncthreads();
    float s = 0.f;
    for (int i = tid; i < NWAVES; i += 256) s += ps[i] * expf(pm[i] - M);
    sm[tid] = s;
    __syncthreads();
    for (int st = 128; st > 0; st >>= 1) {
        if (tid < st) sm[tid] += sm[tid + st];
        __syncthreads();
    }
    if (tid == 0) {
        float lse = M + logf(sm[0]);
        ws[SC_OFF + S_BU + b] = lse - out[(size_t)b * C_ + tgt[b]];
    }
}

// ---- K5: combine ----
__global__ void finalize(const float* __restrict__ ws, float* __restrict__ out0) {
    if (threadIdx.x == 0 && blockIdx.x == 0) {
        float bu = 0.f;
        for (int b = 0; b < 32; ++b) bu += ws[SC_OFF + S_BU + b];
        bu /= 32.f;
        float h = ws[SC_OFF + S_HLOSS];
        float th = 0.f;
        float cnt = ws[SC_OFF + S_THCNT];
        if (ws[SC_OFF + S_BAD] == 0.f && cnt > 0.f) th = ws[SC_OFF + S_THSUM] / cnt;
        out0[0] = 1.0f * bu + 1.0f * h + 3.0f * th;
    }
}

extern "C" void kernel_launch(void* const* d_in, const int* in_sizes, int n_in,
                              void* d_out, int out_size, void* d_ws, size_t ws_size,
                              hipStream_t stream) {
    const float* in = (const float*)d_in[0];
    const float* V = (const float*)d_in[1];
    const int* tgt = (const int*)d_in[2];
    float* outp = (float*)d_out;
    float* ws = (float*)d_ws;
    unsigned short* Af = (unsigned short*)(ws + AF_OFF);

    (void)hipMemsetAsync((void*)(ws + SC_OFF), 0, SC_FLOATS * sizeof(float), stream);

    build_Afrag<<<NSTEP, 256, 0, stream>>>(in, V, tgt, Af);
    sims_dots<<<32, 256, 0, stream>>>(in, ws + DT_OFF);
    small_finish<<<1, 1024, 0, stream>>>(in, V, tgt, ws);

    gemm_mfma<<<NWAVES / 4, 256, 0, stream>>>(V, Af, outp + 1, ws);

    lse_combine<<<B_, 256, 0, stream>>>(outp + 1, tgt, ws);
    finalize<<<1, 64, 0, stream>>>(ws, outp);
}